// Round 9
// baseline (307.339 us; speedup 1.0000x reference)
//
#include <hip/hip_runtime.h>

typedef unsigned short u16;
typedef unsigned int u32;
typedef unsigned long long u64;
typedef _Float16 f16x8 __attribute__((ext_vector_type(8)));
typedef float f32x4 __attribute__((ext_vector_type(4)));

__device__ __forceinline__ u16 f2h(float f) {
    _Float16 h = (_Float16)f;
    return __builtin_bit_cast(u16, h);
}

// ---------------- conv1d(256->128,k=3,pad=1)+ReLU -> hC fp16 [b][c][t] ----------------
__global__ void conv_kernel(const float* __restrict__ x, const float* __restrict__ w,
                            const float* __restrict__ bias, u16* __restrict__ hC) {
    int co = blockIdx.x, b = blockIdx.y, t = threadIdx.x;  // 128 threads
    float acc = bias[co];
    const float* xb = x + b * 256 * 128;
    const float* wr = w + co * 768;
    for (int ci = 0; ci < 256; ++ci) {
        float w0 = wr[ci * 3 + 0], w1 = wr[ci * 3 + 1], w2 = wr[ci * 3 + 2];
        float x1 = xb[ci * 128 + t];
        float x0 = (t >= 1)   ? xb[ci * 128 + t - 1] : 0.f;
        float x2 = (t < 127) ? xb[ci * 128 + t + 1] : 0.f;
        acc += x0 * w0 + x1 * w1 + x2 * w2;
    }
    hC[b * 16384 + co * 128 + t] = f2h(fmaxf(acc, 0.f));   // coalesced in t
}

// ---------------- prep: 0..255 cvt W2; 256: tab; 257: c0 ----------------
__global__ void prep_kernel(const float* __restrict__ w2d, const float* __restrict__ b3,
                            const float* __restrict__ b2, int* __restrict__ tab,
                            u16* __restrict__ W2h, float* __restrict__ c0) {
    if (blockIdx.x < 256) {
        int i = blockIdx.x * 256 + threadIdx.x;
        W2h[i] = f2h(w2d[i]);
        return;
    }
    if (blockIdx.x == 256) {
        for (int cell = threadIdx.x; cell < 8256; cell += 256) {
            int off = 0, d = 0;
            while (d < 128) { int w = 128 - d; if (cell < off + w) break; off += w; ++d; }
            tab[cell] = (d << 8) | (cell - off);
        }
        return;
    }
    int o2 = threadIdx.x >> 1, half = threadIdx.x & 1;
    float s = 0.f;
    const float* row = w2d + o2 * 512 + half * 256;
    for (int o = 0; o < 256; ++o) s += row[o] * fmaxf(b3[half * 256 + o], 0.f);
    s += __shfl_xor(s, 1);
    if (half == 0) c0[o2] = fmaxf(s + b2[o2], 0.f);
}

// ---------------- fp32 -> fp16 convert (W3) ----------------
__global__ void cvt_kernel(const float* __restrict__ src, u16* __restrict__ dst, int n) {
    int i = blockIdx.x * blockDim.x + threadIdx.x;
    if (i < n) dst[i] = f2h(src[i]);
}

// ---------------- fill invalid cells with c0 ----------------
__global__ void fill_kernel(const float* __restrict__ c0, float* __restrict__ out) {
    int d = blockIdx.x, b = blockIdx.y;
    if (d == 0) return;
    int cnt = d, total = 128 * cnt;
    for (int idx = threadIdx.x; idx < total; idx += blockDim.x) {
        int o2 = idx / cnt, m = 128 - cnt + (idx % cnt);
        out[((size_t)b << 21) + ((size_t)o2 << 14) + (d << 7) + m] = c0[o2];
    }
}

// ---------------- MFMA mb: MBt[(b,cell)][(c,n)] = sum_t SM[t][n] * h[b][t][c] ----------
// 258 blocks x 32 cells. LDS: hCs [256 rows=(b,c)][128 t] fp16 64KB (XOR-swizzled via
// pre-swizzled global source) + SMs [128 rows=(cell,n)][128 t] fp16 32KB (swizzled build).
// Taps (bit-exact doubles, cliff at s==-1.0) accumulate into an 8-slot register window
// (span <= 8: step <= 2.69), one fp16 row write. 8 groups x 512 MFMA per block.
__global__ __launch_bounds__(256) void mb_mfma(const u16* __restrict__ hC,
                                               const int* __restrict__ tab,
                                               u16* __restrict__ MBt) {
#pragma clang fp contract(off)
    __shared__ alignas(16) u16 hCs[256 * 128];
    __shared__ alignas(16) u16 SMs[128 * 128];
    const int tid = threadIdx.x;
    const int lane = tid & 63, wv = tid >> 6;
    const int fr = lane & 15, fq = lane >> 4;
    const int c0 = blockIdx.x * 32;

#pragma unroll
    for (int i = 0; i < 16; ++i) {              // stage hC 64KB
        int off = i * 4096 + tid * 16;
        int row = off >> 8, colb = off & 255;
        int scol = colb ^ ((row & 7) << 4);
        const u16* g = hC + row * 128 + (scol >> 1);
        __builtin_amdgcn_global_load_lds(
            (const __attribute__((address_space(1))) void*)g,
            (__attribute__((address_space(3))) void*)((char*)hCs + off), 16, 0, 0);
    }
    asm volatile("s_waitcnt vmcnt(0)" ::: "memory");
    __syncthreads();

    for (int g = 0; g < 8; ++g) {
        __syncthreads();                        // prev group's SM readers done
#pragma unroll
        for (int i = 0; i < 8; ++i)             // zero SMs (32KB)
            ((f32x4*)SMs)[i * 256 + tid] = (f32x4){0.f, 0.f, 0.f, 0.f};
        __syncthreads();
        if (tid < 128) {                        // build 4 cells x 32 n
            int n = tid & 31;
            int cell = c0 + g * 4 + (tid >> 5);
            int dm = tab[cell];
            int d = dm >> 8, m = dm & 255;
            double xm = m - (d + 1) * 0.5;
            double step = (2 * d + 1) / 95.0;
            double p0 = step * (double)(3 * n);
            int t0 = (int)floor(xm + p0);
            double w[8] = {0, 0, 0, 0, 0, 0, 0, 0};
#pragma unroll
            for (int j = 0; j < 3; ++j) {
                double p = step * (double)(3 * n + j);  // mul then add: matches numpy
                double s = xm + p;
                double tr = trunc(s);
                double dec = s - tr;
                int dn = (int)tr;
                int up = (int)ceil(s);
                w[dn - t0] += (1.0 - dec) * (1.0 / 3.0);
                w[up - t0] += dec * (1.0 / 3.0);
            }
#pragma unroll
            for (int i = 0; i < 8; ++i) {
                int t = t0 + i;
                if (t >= 0 && t <= 127)
                    SMs[tid * 128 + (t ^ ((tid & 7) << 3))] = f2h((float)w[i]);
            }
        }
        __syncthreads();

        f32x4 acc[2][16];
#pragma unroll
        for (int mt = 0; mt < 2; ++mt)
#pragma unroll
            for (int nt = 0; nt < 16; ++nt) acc[mt][nt] = (f32x4){0.f, 0.f, 0.f, 0.f};
#pragma unroll
        for (int k = 0; k < 4; ++k) {
            int kb = k * 64 + fq * 16;          // byte col in 256B row
            f16x8 af[2];
#pragma unroll
            for (int mt = 0; mt < 2; ++mt) {
                int mr = wv * 32 + mt * 16 + fr;
                af[mt] = *(const f16x8*)((const char*)SMs + mr * 256 + (kb ^ ((mr & 7) << 4)));
            }
#pragma unroll
            for (int nt = 0; nt < 16; ++nt) {
                int br = nt * 16 + fr;
                f16x8 bf = *(const f16x8*)((const char*)hCs + br * 256 + (kb ^ ((br & 7) << 4)));
                acc[0][nt] = __builtin_amdgcn_mfma_f32_16x16x32_f16(af[0], bf, acc[0][nt], 0, 0, 0);
                acc[1][nt] = __builtin_amdgcn_mfma_f32_16x16x32_f16(af[1], bf, acc[1][nt], 0, 0, 0);
            }
        }
        // store: m = wv*32+mt*16+fq*4+r -> (cl = m>>5, n = m&31); nn = nt*16+fr -> (b, c)
#pragma unroll
        for (int mt = 0; mt < 2; ++mt) {
            int mbase = wv * 32 + mt * 16 + (fq << 2);
            int cl = mbase >> 5, n0 = mbase & 31;
            size_t rowb = (size_t)(c0 + g * 4 + cl);
#pragma unroll
            for (int nt = 0; nt < 16; ++nt) {
                int nn = nt * 16 + fr;
                int b = nn >> 7, c = nn & 127;
                f32x4 v = acc[mt][nt];
                u64 pw = 0;
#pragma unroll
                for (int r = 0; r < 4; ++r) pw |= (u64)f2h(v[r]) << (16 * r);
                *(u64*)(MBt + ((size_t)b * 8256 + rowb) * 4096 + c * 32 + n0) = pw;
            }
        }
    }
}

// ---------------- GEMM1: m3T[row=bcell][512 o] = relu(W3h . MBt^T + b3) ----------------
// Grid 520 = 130 panels x 4 o-splits (quad-XCD co-location). BM=128, BN=128, BK=64,
// 4 waves 64x64, LDS 64KB dbuf -> 2 blocks/CU. Counted vmcnt(8), XOR swizzle.
__global__ __launch_bounds__(256, 2) void mega_kernel(
        const u16* __restrict__ W3h, const u16* __restrict__ MBt,
        const float* __restrict__ b3, u16* __restrict__ m3T) {
    __shared__ alignas(16) char lds[65536];

    const int tid = threadIdx.x;
    const int lane = tid & 63, wv = tid >> 6;
    const int fr = lane & 15, fq = lane >> 4;
    const int swz = (fr & 7) << 4;
    const int wm = wv >> 1, wn = wv & 1;

    int i = blockIdx.x, q, s;
    if (i < 512) { int c = i >> 5, r = i & 31; s = r >> 3; q = c * 8 + (r & 7); }
    else         { int t2 = i - 512; q = 128 + (t2 >> 2); s = t2 & 3; }
    const int b = (q >= 65) ? 1 : 0;
    const int pi = q - 65 * b;
    const int cell0 = pi * 128;
    const int cn = (pi == 64) ? 64 : 128;
    const size_t brow0 = (size_t)b * 8256 + cell0;
    const int m0 = s * 128;

    f32x4 acc[4][4] = {};

    auto stage = [&](int buf, int kt) {
        char* A = lds + buf * 16384;
        char* B = lds + 32768 + buf * 16384;
#pragma unroll
        for (int i2 = 0; i2 < 4; ++i2) {
            int off = i2 * 4096 + tid * 16;
            int row = off >> 7, colb = off & 127;
            int scol = colb ^ ((row & 7) << 4);
            const u16* ga = W3h + (size_t)(m0 + row) * 4096 + kt + (scol >> 1);
            __builtin_amdgcn_global_load_lds(
                (const __attribute__((address_space(1))) void*)ga,
                (__attribute__((address_space(3))) void*)(A + off), 16, 0, 0);
        }
#pragma unroll
        for (int i2 = 0; i2 < 4; ++i2) {
            int off = i2 * 4096 + tid * 16;
            int row = off >> 7, colb = off & 127;
            int r2 = row < cn ? row : 0;
            int scol = colb ^ ((row & 7) << 4);
            const u16* gb = MBt + (brow0 + r2) * 4096 + kt + (scol >> 1);
            __builtin_amdgcn_global_load_lds(
                (const __attribute__((address_space(1))) void*)gb,
                (__attribute__((address_space(3))) void*)(B + off), 16, 0, 0);
        }
    };

    stage(0, 0);
    stage(1, 64);
    asm volatile("s_waitcnt vmcnt(8)" ::: "memory");
    __builtin_amdgcn_sched_barrier(0);
    __builtin_amdgcn_s_barrier();
    __builtin_amdgcn_sched_barrier(0);

    for (int t = 0; t < 64; ++t) {
        const int cur = t & 1;
        const char* A = lds + cur * 16384;
        const char* Bp = lds + 32768 + cur * 16384;
#pragma unroll
        for (int kk = 0; kk < 2; ++kk) {
            const int kb = (kk * 64 + (fq << 4)) ^ swz;
            f16x8 af[4], bfr[4];
#pragma unroll
            for (int mf = 0; mf < 4; ++mf)
                af[mf] = *(const f16x8*)(A + (wm * 64 + mf * 16 + fr) * 128 + kb);
#pragma unroll
            for (int nf = 0; nf < 4; ++nf)
                bfr[nf] = *(const f16x8*)(Bp + (wn * 64 + nf * 16 + fr) * 128 + kb);
            __builtin_amdgcn_s_setprio(1);
#pragma unroll
            for (int mf = 0; mf < 4; ++mf)
#pragma unroll
                for (int nf = 0; nf < 4; ++nf)
                    acc[mf][nf] = __builtin_amdgcn_mfma_f32_16x16x32_f16(
                        af[mf], bfr[nf], acc[mf][nf], 0, 0, 0);
            __builtin_amdgcn_s_setprio(0);
        }
        __builtin_amdgcn_s_barrier();
        if (t < 62) {
            stage(cur, (t + 2) << 6);
            asm volatile("s_waitcnt vmcnt(8)" ::: "memory");
        } else {
            asm volatile("s_waitcnt vmcnt(0)" ::: "memory");
        }
        __builtin_amdgcn_sched_barrier(0);
        __builtin_amdgcn_s_barrier();
        __builtin_amdgcn_sched_barrier(0);
    }

#pragma unroll
    for (int mf = 0; mf < 4; ++mf) {
        int o = m0 + wm * 64 + mf * 16 + (fq << 2);
#pragma unroll
        for (int nf = 0; nf < 4; ++nf) {
            int cl = wn * 64 + nf * 16 + fr;
            if (cl < cn) {
                f32x4 v = acc[mf][nf];
                u64 pw = 0;
#pragma unroll
                for (int r = 0; r < 4; ++r) {
                    float z = fmaxf(v[r] + b3[o + r], 0.f);
                    pw |= (u64)f2h(z) << (16 * r);
                }
                *(u64*)(m3T + (brow0 + cl) * 512 + o) = pw;
            }
        }
    }
}

// ---------------- GEMM2: out = relu(W2 . m3 + b2), scatter via tab ----------------
// BM=64 -> 258 blocks (full GPU). A = m3T[16512][512], B = W2h[128][512].
__global__ __launch_bounds__(256) void gemm2_kernel(const u16* __restrict__ A,
                                                    const u16* __restrict__ B,
                                                    const float* __restrict__ bias,
                                                    const int* __restrict__ tab,
                                                    float* __restrict__ out) {
    __shared__ alignas(16) u16 As[64 * 64];
    __shared__ alignas(16) u16 Bs[128 * 64];
    const int tid = threadIdx.x;
    const int lane = tid & 63, wave = tid >> 6;
    const int m0 = blockIdx.x * 64;
    const int wr = wave & 1, wc = wave >> 1;
    const int fr = lane & 15, fk = (lane >> 4) * 16;
    f32x4 acc[2][4] = {};

    for (int kt = 0; kt < 512; kt += 64) {
#pragma unroll
        for (int i = 0; i < 2; ++i) {
            int off = i * 4096 + tid * 16;
            int row = off >> 7, colb = off & 127;
            const u16* ga = A + (size_t)(m0 + row) * 512 + kt + (colb >> 1);
            __builtin_amdgcn_global_load_lds(
                (const __attribute__((address_space(1))) void*)ga,
                (__attribute__((address_space(3))) void*)((char*)As + off), 16, 0, 0);
        }
#pragma unroll
        for (int i = 0; i < 4; ++i) {
            int off = i * 4096 + tid * 16;
            int row = off >> 7, colb = off & 127;
            const u16* gb = B + (size_t)row * 512 + kt + (colb >> 1);
            __builtin_amdgcn_global_load_lds(
                (const __attribute__((address_space(1))) void*)gb,
                (__attribute__((address_space(3))) void*)((char*)Bs + off), 16, 0, 0);
        }
        __syncthreads();
#pragma unroll
        for (int kk = 0; kk < 2; ++kk) {
            f16x8 af[2], bfr[4];
            const int kb = kk * 64 + fk;
#pragma unroll
            for (int mf = 0; mf < 2; ++mf)
                af[mf] = *(const f16x8*)((const char*)As + (wr * 32 + mf * 16 + fr) * 128 + kb);
#pragma unroll
            for (int nf = 0; nf < 4; ++nf)
                bfr[nf] = *(const f16x8*)((const char*)Bs + (wc * 64 + nf * 16 + fr) * 128 + kb);
#pragma unroll
            for (int mf = 0; mf < 2; ++mf)
#pragma unroll
                for (int nf = 0; nf < 4; ++nf)
                    acc[mf][nf] = __builtin_amdgcn_mfma_f32_16x16x32_f16(
                        af[mf], bfr[nf], acc[mf][nf], 0, 0, 0);
        }
        __syncthreads();
    }

#pragma unroll
    for (int mf = 0; mf < 2; ++mf) {
        int rbase = m0 + wr * 32 + mf * 16 + ((lane >> 4) << 2);
#pragma unroll
        for (int nf = 0; nf < 4; ++nf) {
            int o2 = wc * 64 + nf * 16 + fr;
            f32x4 v = acc[mf][nf];
#pragma unroll
            for (int r = 0; r < 4; ++r) {
                int colg = rbase + r;
                int b = (colg >= 8256) ? 1 : 0;
                int cell = colg - b * 8256;
                int dm = tab[cell];
                float z = fmaxf(v[r] + bias[o2], 0.f);
                out[((size_t)b << 21) + ((size_t)o2 << 14) + ((dm >> 8) << 7) + (dm & 255)] = z;
            }
        }
    }
}

// ws layout (bytes):
//   0        hC16    fp16 [2][128][128]            65536
//   131072   W3h     fp16 [512][4096]              4194304
//   4325376  W2h     fp16 [128][512]               131072
//   4456448  c0      fp32 [128]                    512
//   4456960  tab     int  [8256] (alloc 16512)     66048
//   4523008  m3T     fp16 [16512][512]             16908288
//   21562368 MBt     fp16 [16512][4096]            135266304
extern "C" void kernel_launch(void* const* d_in, const int* in_sizes, int n_in,
                              void* d_out, int out_size, void* d_ws, size_t ws_size,
                              hipStream_t stream) {
    const float* x     = (const float*)d_in[0];
    const float* w_red = (const float*)d_in[1];
    const float* b_red = (const float*)d_in[2];
    const float* w3d   = (const float*)d_in[3];
    const float* b3d   = (const float*)d_in[4];
    const float* w2d   = (const float*)d_in[5];
    const float* b2d   = (const float*)d_in[6];
    float* out = (float*)d_out;

    char* ws = (char*)d_ws;
    u16*   hC  = (u16*)(ws + 0);
    u16*   W3h = (u16*)(ws + 131072);
    u16*   W2h = (u16*)(ws + 4325376);
    float* c0  = (float*)(ws + 4456448);
    int*   tab = (int*)(ws + 4456960);
    u16*   m3T = (u16*)(ws + 4523008);
    u16*   MBt = (u16*)(ws + 21562368);

    conv_kernel<<<dim3(128, 2), 128, 0, stream>>>(x, w_red, b_red, hC);
    prep_kernel<<<258, 256, 0, stream>>>(w2d, b3d, b2d, tab, W2h, c0);
    cvt_kernel<<<8192, 256, 0, stream>>>(w3d, W3h, 2097152);
    mb_mfma<<<258, 256, 0, stream>>>(hC, tab, MBt);
    mega_kernel<<<520, 256, 0, stream>>>(W3h, MBt, b3d, m3T);
    gemm2_kernel<<<258, 256, 0, stream>>>(m3T, W2h, b2d, tab, out);
    fill_kernel<<<dim3(128, 2), 256, 0, stream>>>(c0, out);
}

// Round 10
// 266.350 us; speedup vs baseline: 1.1539x; 1.1539x over previous
//
#include <hip/hip_runtime.h>

typedef unsigned short u16;
typedef unsigned int u32;
typedef unsigned long long u64;
typedef _Float16 f16x8 __attribute__((ext_vector_type(8)));
typedef float f32x4 __attribute__((ext_vector_type(4)));

__device__ __forceinline__ u16 f2h(float f) {
    _Float16 h = (_Float16)f;
    return __builtin_bit_cast(u16, h);
}

// ---------------- setup: W3 cvt + conv + W2 cvt + tab + c0 in ONE launch ----------------
// blocks [0,8192): W3 cvt; [8192,8448): conv (co,b); [8448,8704): W2 cvt; 8704: tab; 8705: c0
__global__ void setup_kernel(const float* __restrict__ x, const float* __restrict__ w_red,
                             const float* __restrict__ b_red, const float* __restrict__ w3d,
                             const float* __restrict__ w2d, const float* __restrict__ b3,
                             const float* __restrict__ b2,
                             u16* __restrict__ W3h, u16* __restrict__ hC,
                             u16* __restrict__ W2h, int* __restrict__ tab,
                             float* __restrict__ c0) {
    int bid = blockIdx.x, tid = threadIdx.x;
    if (bid < 8192) {                      // W3 fp32->fp16
        int i = bid * 256 + tid;
        W3h[i] = f2h(w3d[i]);
        return;
    }
    if (bid < 8448) {                      // conv1d(256->128,k3,pad1)+ReLU -> hC[b][c][t]
        if (tid >= 128) return;
        int idx = bid - 8192;
        int co = idx & 127, b = idx >> 7, t = tid;
        float acc = b_red[co];
        const float* xb = x + b * 256 * 128;
        const float* wr = w_red + co * 768;
        for (int ci = 0; ci < 256; ++ci) {
            float w0 = wr[ci * 3 + 0], w1 = wr[ci * 3 + 1], w2 = wr[ci * 3 + 2];
            float x1 = xb[ci * 128 + t];
            float x0 = (t >= 1)   ? xb[ci * 128 + t - 1] : 0.f;
            float x2 = (t < 127) ? xb[ci * 128 + t + 1] : 0.f;
            acc += x0 * w0 + x1 * w1 + x2 * w2;
        }
        hC[b * 16384 + co * 128 + t] = f2h(fmaxf(acc, 0.f));
        return;
    }
    if (bid < 8704) {                      // W2 fp32->fp16
        int i = (bid - 8448) * 256 + tid;
        W2h[i] = f2h(w2d[i]);
        return;
    }
    if (bid == 8704) {                     // cell -> (d,m)
        for (int cell = tid; cell < 8256; cell += 256) {
            int off = 0, d = 0;
            while (d < 128) { int w = 128 - d; if (cell < off + w) break; off += w; ++d; }
            tab[cell] = (d << 8) | (cell - off);
        }
        return;
    }
    // c0 for invalid cells
    int o2 = tid >> 1, half = tid & 1;
    float s = 0.f;
    const float* row = w2d + o2 * 512 + half * 256;
    for (int o = 0; o < 256; ++o) s += row[o] * fmaxf(b3[half * 256 + o], 0.f);
    s += __shfl_xor(s, 1);
    if (half == 0) c0[o2] = fmaxf(s + b2[o2], 0.f);
}

// ---------------- fill invalid cells with c0 ----------------
__global__ void fill_kernel(const float* __restrict__ c0, float* __restrict__ out) {
    int d = blockIdx.x, b = blockIdx.y;
    if (d == 0) return;
    int cnt = d, total = 128 * cnt;
    for (int idx = threadIdx.x; idx < total; idx += blockDim.x) {
        int o2 = idx / cnt, m = 128 - cnt + (idx % cnt);
        out[((size_t)b << 21) + ((size_t)o2 << 14) + (d << 7) + m] = c0[o2];
    }
}

// ---------------- mb_mfma v2: MBt = SM . h via MFMA; scratch-free taps ----------------
// 258 blocks x 32 cells. LDS: hCs 64KB + SMs dbuf 2x32KB + tap table 20KB = 148KB.
// Tap table built ONCE (all-static w composition -> no localMem). Per group: builders
// (tid<128) zero+scatter ONLY their own 256B row into SMs[buf^1] (no zero-phase barrier),
// overlapping other waves' MFMA; ONE barrier per group. Tap doubles bit-match numpy
// (mul-then-add, contract off; window span<=7 proven by step<=2.69; R9-verified).
__global__ __launch_bounds__(256) void mb_mfma(const u16* __restrict__ hC,
                                               const int* __restrict__ tab,
                                               u16* __restrict__ MBt) {
#pragma clang fp contract(off)
    __shared__ alignas(16) u16 hCs[256 * 128];
    __shared__ alignas(16) u16 SMs[2][128 * 128];
    __shared__ alignas(16) u16 wtab[1024][8];
    __shared__ int t0s[1024];
    const int tid = threadIdx.x;
    const int lane = tid & 63, wv = tid >> 6;
    const int fr = lane & 15, fq = lane >> 4;
    const int c0 = blockIdx.x * 32;

#pragma unroll
    for (int i = 0; i < 16; ++i) {              // stage hC 64KB (swizzled source)
        int off = i * 4096 + tid * 16;
        int row = off >> 8, colb = off & 255;
        int scol = colb ^ ((row & 7) << 4);
        const u16* g = hC + row * 128 + (scol >> 1);
        __builtin_amdgcn_global_load_lds(
            (const __attribute__((address_space(1))) void*)g,
            (__attribute__((address_space(3))) void*)((char*)hCs + off), 16, 0, 0);
    }

    // tap table: 4 entries/thread; w window composed with STATIC indices only
#pragma unroll
    for (int ii = 0; ii < 4; ++ii) {
        int e = tid + (ii << 8);
        int cell = c0 + (e >> 5), n = e & 31;
        int dm = tab[cell];
        int d = dm >> 8, m = dm & 255;
        double xm = m - (d + 1) * 0.5;
        double step = (2 * d + 1) / 95.0;
        int t0 = (int)floor(xm + step * (double)(3 * n));
        int dnr[3], upr[3];
        double av[3], bv[3];
#pragma unroll
        for (int j = 0; j < 3; ++j) {
            double p = step * (double)(3 * n + j);   // mul then add: matches numpy
            double s = xm + p;
            double tr = trunc(s);
            double dec = s - tr;
            int dn = (int)tr, up = (int)ceil(s);
            dnr[j] = dn - t0; upr[j] = up - t0;
            av[j] = (dn >= 0 && dn <= 127) ? (1.0 - dec) * (1.0 / 3.0) : 0.0;
            bv[j] = (up >= 0 && up <= 127) ? dec * (1.0 / 3.0) : 0.0;
        }
#pragma unroll
        for (int sl = 0; sl < 8; ++sl) {
            double a = 0.0;
#pragma unroll
            for (int j = 0; j < 3; ++j) {
                a += (dnr[j] == sl) ? av[j] : 0.0;
                a += (upr[j] == sl) ? bv[j] : 0.0;
            }
            wtab[e][sl] = f2h((float)a);
        }
        t0s[e] = t0;
    }
    asm volatile("s_waitcnt vmcnt(0)" ::: "memory");
    __syncthreads();

    auto build = [&](int g, int buf) {          // builder owns its row: zero + scatter
        if (tid < 128) {
            int e = (g << 7) + tid;
            int t0 = t0s[e];
            char* row = (char*)(SMs[buf] + tid * 128);
            int swzB = (tid & 7) << 4;
            f32x4 z = {0.f, 0.f, 0.f, 0.f};
#pragma unroll
            for (int ch = 0; ch < 16; ++ch)
                *(f32x4*)(row + ((ch * 16) ^ swzB)) = z;
#pragma unroll
            for (int i = 0; i < 8; ++i) {
                int t = t0 + i;
                if (t >= 0 && t <= 127)
                    *(u16*)(row + ((t << 1) ^ swzB)) = wtab[e][i];
            }
        }
    };

    build(0, 0);
    __syncthreads();
    for (int g = 0; g < 8; ++g) {
        const int buf = g & 1;
        if (g < 7) build(g + 1, buf ^ 1);       // overlaps MFMA of other waves

        f32x4 acc[2][16];
#pragma unroll
        for (int mt = 0; mt < 2; ++mt)
#pragma unroll
            for (int nt = 0; nt < 16; ++nt) acc[mt][nt] = (f32x4){0.f, 0.f, 0.f, 0.f};
#pragma unroll
        for (int k = 0; k < 4; ++k) {
            int kb = k * 64 + fq * 16;
            f16x8 af[2];
#pragma unroll
            for (int mt = 0; mt < 2; ++mt) {
                int mr = wv * 32 + mt * 16 + fr;
                af[mt] = *(const f16x8*)((const char*)SMs[buf] + mr * 256 + (kb ^ ((mr & 7) << 4)));
            }
#pragma unroll
            for (int nt = 0; nt < 16; ++nt) {
                int br = nt * 16 + fr;
                f16x8 bf = *(const f16x8*)((const char*)hCs + br * 256 + (kb ^ ((br & 7) << 4)));
                acc[0][nt] = __builtin_amdgcn_mfma_f32_16x16x32_f16(af[0], bf, acc[0][nt], 0, 0, 0);
                acc[1][nt] = __builtin_amdgcn_mfma_f32_16x16x32_f16(af[1], bf, acc[1][nt], 0, 0, 0);
            }
        }
#pragma unroll
        for (int mt = 0; mt < 2; ++mt) {
            int mbase = wv * 32 + mt * 16 + (fq << 2);
            int cl = mbase >> 5, n0 = mbase & 31;
            size_t rowb = (size_t)(c0 + g * 4 + cl);
#pragma unroll
            for (int nt = 0; nt < 16; ++nt) {
                int nn = nt * 16 + fr;
                int b = nn >> 7, c = nn & 127;
                f32x4 v = acc[mt][nt];
                u64 pw = 0;
#pragma unroll
                for (int r = 0; r < 4; ++r) pw |= (u64)f2h(v[r]) << (16 * r);
                *(u64*)(MBt + ((size_t)b * 8256 + rowb) * 4096 + c * 32 + n0) = pw;
            }
        }
        __syncthreads();                        // one barrier per group
    }
}

// ---------------- GEMM1: m3T[row=bcell][512 o] = relu(W3h . MBt^T + b3) ----------------
// Grid 520 = 130 panels x 4 o-splits (quad-XCD co-location). BM=128, BN=128, BK=64,
// 4 waves 64x64, LDS 64KB dbuf -> 2 blocks/CU. Counted vmcnt(8), XOR swizzle.
__global__ __launch_bounds__(256, 2) void mega_kernel(
        const u16* __restrict__ W3h, const u16* __restrict__ MBt,
        const float* __restrict__ b3, u16* __restrict__ m3T) {
    __shared__ alignas(16) char lds[65536];

    const int tid = threadIdx.x;
    const int lane = tid & 63, wv = tid >> 6;
    const int fr = lane & 15, fq = lane >> 4;
    const int swz = (fr & 7) << 4;
    const int wm = wv >> 1, wn = wv & 1;

    int i = blockIdx.x, q, s;
    if (i < 512) { int c = i >> 5, r = i & 31; s = r >> 3; q = c * 8 + (r & 7); }
    else         { int t2 = i - 512; q = 128 + (t2 >> 2); s = t2 & 3; }
    const int b = (q >= 65) ? 1 : 0;
    const int pi = q - 65 * b;
    const int cell0 = pi * 128;
    const int cn = (pi == 64) ? 64 : 128;
    const size_t brow0 = (size_t)b * 8256 + cell0;
    const int m0 = s * 128;

    f32x4 acc[4][4] = {};

    auto stage = [&](int buf, int kt) {
        char* A = lds + buf * 16384;
        char* B = lds + 32768 + buf * 16384;
#pragma unroll
        for (int i2 = 0; i2 < 4; ++i2) {
            int off = i2 * 4096 + tid * 16;
            int row = off >> 7, colb = off & 127;
            int scol = colb ^ ((row & 7) << 4);
            const u16* ga = W3h + (size_t)(m0 + row) * 4096 + kt + (scol >> 1);
            __builtin_amdgcn_global_load_lds(
                (const __attribute__((address_space(1))) void*)ga,
                (__attribute__((address_space(3))) void*)(A + off), 16, 0, 0);
        }
#pragma unroll
        for (int i2 = 0; i2 < 4; ++i2) {
            int off = i2 * 4096 + tid * 16;
            int row = off >> 7, colb = off & 127;
            int r2 = row < cn ? row : 0;
            int scol = colb ^ ((row & 7) << 4);
            const u16* gb = MBt + (brow0 + r2) * 4096 + kt + (scol >> 1);
            __builtin_amdgcn_global_load_lds(
                (const __attribute__((address_space(1))) void*)gb,
                (__attribute__((address_space(3))) void*)(B + off), 16, 0, 0);
        }
    };

    stage(0, 0);
    stage(1, 64);
    asm volatile("s_waitcnt vmcnt(8)" ::: "memory");
    __builtin_amdgcn_sched_barrier(0);
    __builtin_amdgcn_s_barrier();
    __builtin_amdgcn_sched_barrier(0);

    for (int t = 0; t < 64; ++t) {
        const int cur = t & 1;
        const char* A = lds + cur * 16384;
        const char* Bp = lds + 32768 + cur * 16384;
#pragma unroll
        for (int kk = 0; kk < 2; ++kk) {
            const int kb = (kk * 64 + (fq << 4)) ^ swz;
            f16x8 af[4], bfr[4];
#pragma unroll
            for (int mf = 0; mf < 4; ++mf)
                af[mf] = *(const f16x8*)(A + (wm * 64 + mf * 16 + fr) * 128 + kb);
#pragma unroll
            for (int nf = 0; nf < 4; ++nf)
                bfr[nf] = *(const f16x8*)(Bp + (wn * 64 + nf * 16 + fr) * 128 + kb);
            __builtin_amdgcn_s_setprio(1);
#pragma unroll
            for (int mf = 0; mf < 4; ++mf)
#pragma unroll
                for (int nf = 0; nf < 4; ++nf)
                    acc[mf][nf] = __builtin_amdgcn_mfma_f32_16x16x32_f16(
                        af[mf], bfr[nf], acc[mf][nf], 0, 0, 0);
            __builtin_amdgcn_s_setprio(0);
        }
        __builtin_amdgcn_s_barrier();
        if (t < 62) {
            stage(cur, (t + 2) << 6);
            asm volatile("s_waitcnt vmcnt(8)" ::: "memory");
        } else {
            asm volatile("s_waitcnt vmcnt(0)" ::: "memory");
        }
        __builtin_amdgcn_sched_barrier(0);
        __builtin_amdgcn_s_barrier();
        __builtin_amdgcn_sched_barrier(0);
    }

#pragma unroll
    for (int mf = 0; mf < 4; ++mf) {
        int o = m0 + wm * 64 + mf * 16 + (fq << 2);
#pragma unroll
        for (int nf = 0; nf < 4; ++nf) {
            int cl = wn * 64 + nf * 16 + fr;
            if (cl < cn) {
                f32x4 v = acc[mf][nf];
                u64 pw = 0;
#pragma unroll
                for (int r = 0; r < 4; ++r) {
                    float z = fmaxf(v[r] + b3[o + r], 0.f);
                    pw |= (u64)f2h(z) << (16 * r);
                }
                *(u64*)(m3T + (brow0 + cl) * 512 + o) = pw;
            }
        }
    }
}

// ---------------- GEMM2: out = relu(W2 . m3 + b2), scatter via tab ----------------
__global__ __launch_bounds__(256) void gemm2_kernel(const u16* __restrict__ A,
                                                    const u16* __restrict__ B,
                                                    const float* __restrict__ bias,
                                                    const int* __restrict__ tab,
                                                    float* __restrict__ out) {
    __shared__ alignas(16) u16 As[64 * 64];
    __shared__ alignas(16) u16 Bs[128 * 64];
    const int tid = threadIdx.x;
    const int lane = tid & 63, wave = tid >> 6;
    const int m0 = blockIdx.x * 64;
    const int wr = wave & 1, wc = wave >> 1;
    const int fr = lane & 15, fk = (lane >> 4) * 16;
    f32x4 acc[2][4] = {};

    for (int kt = 0; kt < 512; kt += 64) {
#pragma unroll
        for (int i = 0; i < 2; ++i) {
            int off = i * 4096 + tid * 16;
            int row = off >> 7, colb = off & 127;
            const u16* ga = A + (size_t)(m0 + row) * 512 + kt + (colb >> 1);
            __builtin_amdgcn_global_load_lds(
                (const __attribute__((address_space(1))) void*)ga,
                (__attribute__((address_space(3))) void*)((char*)As + off), 16, 0, 0);
        }
#pragma unroll
        for (int i = 0; i < 4; ++i) {
            int off = i * 4096 + tid * 16;
            int row = off >> 7, colb = off & 127;
            const u16* gb = B + (size_t)row * 512 + kt + (colb >> 1);
            __builtin_amdgcn_global_load_lds(
                (const __attribute__((address_space(1))) void*)gb,
                (__attribute__((address_space(3))) void*)((char*)Bs + off), 16, 0, 0);
        }
        __syncthreads();
#pragma unroll
        for (int kk = 0; kk < 2; ++kk) {
            f16x8 af[2], bfr[4];
            const int kb = kk * 64 + fk;
#pragma unroll
            for (int mf = 0; mf < 2; ++mf)
                af[mf] = *(const f16x8*)((const char*)As + (wr * 32 + mf * 16 + fr) * 128 + kb);
#pragma unroll
            for (int nf = 0; nf < 4; ++nf)
                bfr[nf] = *(const f16x8*)((const char*)Bs + (wc * 64 + nf * 16 + fr) * 128 + kb);
#pragma unroll
            for (int mf = 0; mf < 2; ++mf)
#pragma unroll
                for (int nf = 0; nf < 4; ++nf)
                    acc[mf][nf] = __builtin_amdgcn_mfma_f32_16x16x32_f16(
                        af[mf], bfr[nf], acc[mf][nf], 0, 0, 0);
        }
        __syncthreads();
    }

#pragma unroll
    for (int mf = 0; mf < 2; ++mf) {
        int rbase = m0 + wr * 32 + mf * 16 + ((lane >> 4) << 2);
#pragma unroll
        for (int nf = 0; nf < 4; ++nf) {
            int o2 = wc * 64 + nf * 16 + fr;
            f32x4 v = acc[mf][nf];
#pragma unroll
            for (int r = 0; r < 4; ++r) {
                int colg = rbase + r;
                int b = (colg >= 8256) ? 1 : 0;
                int cell = colg - b * 8256;
                int dm = tab[cell];
                float z = fmaxf(v[r] + bias[o2], 0.f);
                out[((size_t)b << 21) + ((size_t)o2 << 14) + ((dm >> 8) << 7) + (dm & 255)] = z;
            }
        }
    }
}

// ws layout (bytes):
//   0        hC      fp16 [2][128][128]            65536
//   131072   W3h     fp16 [512][4096]              4194304
//   4325376  W2h     fp16 [128][512]               131072
//   4456448  c0      fp32 [128]                    512
//   4456960  tab     int  [8256] (alloc 16512)     66048
//   4523008  m3T     fp16 [16512][512]             16908288
//   21562368 MBt     fp16 [16512][4096]            135266304
extern "C" void kernel_launch(void* const* d_in, const int* in_sizes, int n_in,
                              void* d_out, int out_size, void* d_ws, size_t ws_size,
                              hipStream_t stream) {
    const float* x     = (const float*)d_in[0];
    const float* w_red = (const float*)d_in[1];
    const float* b_red = (const float*)d_in[2];
    const float* w3d   = (const float*)d_in[3];
    const float* b3d   = (const float*)d_in[4];
    const float* w2d   = (const float*)d_in[5];
    const float* b2d   = (const float*)d_in[6];
    float* out = (float*)d_out;

    char* ws = (char*)d_ws;
    u16*   hC  = (u16*)(ws + 0);
    u16*   W3h = (u16*)(ws + 131072);
    u16*   W2h = (u16*)(ws + 4325376);
    float* c0  = (float*)(ws + 4456448);
    int*   tab = (int*)(ws + 4456960);
    u16*   m3T = (u16*)(ws + 4523008);
    u16*   MBt = (u16*)(ws + 21562368);

    setup_kernel<<<8706, 256, 0, stream>>>(x, w_red, b_red, w3d, w2d, b3d, b2d,
                                           W3h, hC, W2h, tab, c0);
    mb_mfma<<<258, 256, 0, stream>>>(hC, tab, MBt);
    mega_kernel<<<520, 256, 0, stream>>>(W3h, MBt, b3d, m3T);
    gemm2_kernel<<<258, 256, 0, stream>>>(m3T, W2h, b2d, tab, out);
    fill_kernel<<<dim3(128, 2), 256, 0, stream>>>(c0, out);
}

// Round 11
// 239.054 us; speedup vs baseline: 1.2856x; 1.1142x over previous
//
#include <hip/hip_runtime.h>

typedef unsigned short u16;
typedef unsigned int u32;
typedef unsigned long long u64;
typedef _Float16 f16x8 __attribute__((ext_vector_type(8)));
typedef float f32x4 __attribute__((ext_vector_type(4)));

__device__ __forceinline__ u16 f2h(float f) {
    _Float16 h = (_Float16)f;
    return __builtin_bit_cast(u16, h);
}

// ---------------- setup (grid 1802): W3n transpose | conv | W2h | tap table | tab | c0 ----
__global__ void setup_kernel(const float* __restrict__ x, const float* __restrict__ w_red,
                             const float* __restrict__ b_red, const float* __restrict__ w3d,
                             const float* __restrict__ w2d, const float* __restrict__ b3,
                             const float* __restrict__ b2,
                             u16* __restrict__ W3n, u16* __restrict__ hT16,
                             u16* __restrict__ W2h, int* __restrict__ tab,
                             float* __restrict__ c0,
                             int* __restrict__ tapT0, u16* __restrict__ tapW) {
#pragma clang fp contract(off)
    int bid = blockIdx.x, tid = threadIdx.x;
    if (bid < 256) {                       // W3n[n][o*128+c] = fp16(w3d[o][c][n])
        int oc = bid * 256 + tid;
        float4 v[8];
        const float4* src = (const float4*)(w3d + (size_t)oc * 32);
#pragma unroll
        for (int j = 0; j < 8; ++j) v[j] = src[j];
        const float* vf = (const float*)v;
#pragma unroll
        for (int n = 0; n < 32; ++n)
            W3n[n * 65536 + oc] = f2h(vf[n]);   // coalesced per n
        return;
    }
    if (bid < 512) {                       // conv1d+ReLU -> hT16[b][t][c] fp16
        if (tid >= 128) return;
        int idx = bid - 256;
        int co = idx & 127, b = idx >> 7, t = tid;
        float acc = b_red[co];
        const float* xb = x + b * 256 * 128;
        const float* wr = w_red + co * 768;
        for (int ci = 0; ci < 256; ++ci) {
            float w0 = wr[ci * 3 + 0], w1 = wr[ci * 3 + 1], w2 = wr[ci * 3 + 2];
            float x1 = xb[ci * 128 + t];
            float x0 = (t >= 1)   ? xb[ci * 128 + t - 1] : 0.f;
            float x2 = (t < 127) ? xb[ci * 128 + t + 1] : 0.f;
            acc += x0 * w0 + x1 * w1 + x2 * w2;
        }
        hT16[b * 16384 + t * 128 + co] = f2h(fmaxf(acc, 0.f));
        return;
    }
    if (bid < 768) {                       // W2h
        int i = (bid - 512) * 256 + tid;
        W2h[i] = f2h(w2d[i]);
        return;
    }
    if (bid < 1800) {                      // tap table, entry gid = n*8256 + cell
        int gid = (bid - 768) * 256 + tid;
        int n = gid / 8256, cell = gid - n * 8256;
        int off = 0, d = 0;
        while (d < 128) { int w = 128 - d; if (cell < off + w) break; off += w; ++d; }
        int m = cell - off;
        double xm = m - (d + 1) * 0.5;
        double step = (2 * d + 1) / 95.0;
        int t0 = (int)floor(xm + step * (double)(3 * n));
        int dnr[3], upr[3]; double av[3], bv[3];
#pragma unroll
        for (int j = 0; j < 3; ++j) {
            double p = step * (double)(3 * n + j);   // mul then add: matches numpy
            double s = xm + p;
            double tr = trunc(s);
            double dec = s - tr;
            int dn = (int)tr, up = (int)ceil(s);
            dnr[j] = dn - t0; upr[j] = up - t0;
            av[j] = (dn >= 0 && dn <= 127) ? (1.0 - dec) * (1.0 / 3.0) : 0.0;
            bv[j] = (up >= 0 && up <= 127) ? dec * (1.0 / 3.0) : 0.0;
        }
#pragma unroll
        for (int sl = 0; sl < 8; ++sl) {   // static composition (no scratch)
            double a = 0.0;
#pragma unroll
            for (int j = 0; j < 3; ++j) {
                a += (dnr[j] == sl) ? av[j] : 0.0;
                a += (upr[j] == sl) ? bv[j] : 0.0;
            }
            tapW[(size_t)gid * 8 + sl] = f2h((float)a);
        }
        tapT0[gid] = t0;
        return;
    }
    if (bid == 1800) {                     // cell -> (d,m)
        for (int cell = tid; cell < 8256; cell += 256) {
            int off = 0, d = 0;
            while (d < 128) { int w = 128 - d; if (cell < off + w) break; off += w; ++d; }
            tab[cell] = (d << 8) | (cell - off);
        }
        return;
    }
    int o2 = tid >> 1, half = tid & 1;     // c0
    float s = 0.f;
    const float* row = w2d + o2 * 512 + half * 256;
    for (int o = 0; o < 256; ++o) s += row[o] * fmaxf(b3[half * 256 + o], 0.f);
    s += __shfl_xor(s, 1);
    if (half == 0) c0[o2] = fmaxf(s + b2[o2], 0.f);
}

// ---------------- fill invalid cells with c0 ----------------
__global__ void fill_kernel(const float* __restrict__ c0, float* __restrict__ out) {
    int d = blockIdx.x, b = blockIdx.y;
    if (d == 0) return;
    int cnt = d, total = 128 * cnt;
    for (int idx = threadIdx.x; idx < total; idx += blockDim.x) {
        int o2 = idx / cnt, m = 128 - cnt + (idx % cnt);
        out[((size_t)b << 21) + ((size_t)o2 << 14) + (d << 7) + m] = c0[o2];
    }
}

// ---------------- gkern: G[b][o][n*128+t] = sum_c W3n[n][o][c] * hT16[b][t][c] ----------
// 256 blocks = (os 0..3)x(n 0..31)x(b 0..1). Single-shot K=128. 4 waves 64x64.
__global__ __launch_bounds__(256) void gkern(const u16* __restrict__ W3n,
                                             const u16* __restrict__ hT16,
                                             u16* __restrict__ G) {
    __shared__ alignas(16) u16 As[128 * 128];
    __shared__ alignas(16) u16 Bs[128 * 128];
    const int tid = threadIdx.x;
    const int lane = tid & 63, wv = tid >> 6;
    const int fr = lane & 15, fq = lane >> 4;
    const int bid = blockIdx.x;
    const int b = bid & 1, n = (bid >> 1) & 31, os = bid >> 6;
    const u16* Abase = W3n + n * 65536 + os * 128 * 128;
    const u16* Bbase = hT16 + b * 16384;
#pragma unroll
    for (int i = 0; i < 8; ++i) {
        int off = i * 4096 + tid * 16;
        int row = off >> 8, colb = off & 255;
        int scol = colb ^ ((row & 7) << 4);
        __builtin_amdgcn_global_load_lds(
            (const __attribute__((address_space(1))) void*)(Abase + row * 128 + (scol >> 1)),
            (__attribute__((address_space(3))) void*)((char*)As + off), 16, 0, 0);
        __builtin_amdgcn_global_load_lds(
            (const __attribute__((address_space(1))) void*)(Bbase + row * 128 + (scol >> 1)),
            (__attribute__((address_space(3))) void*)((char*)Bs + off), 16, 0, 0);
    }
    asm volatile("s_waitcnt vmcnt(0)" ::: "memory");
    __syncthreads();
    const int wm = wv >> 1, wn = wv & 1;
    f32x4 acc[4][4] = {};
#pragma unroll
    for (int kk = 0; kk < 4; ++kk) {
        int kb = kk * 64 + fq * 16;
        f16x8 af[4], bf[4];
#pragma unroll
        for (int mf = 0; mf < 4; ++mf) {
            int row = wm * 64 + mf * 16 + fr;
            af[mf] = *(const f16x8*)((const char*)As + row * 256 + (kb ^ ((row & 7) << 4)));
        }
#pragma unroll
        for (int nf = 0; nf < 4; ++nf) {
            int row = wn * 64 + nf * 16 + fr;
            bf[nf] = *(const f16x8*)((const char*)Bs + row * 256 + (kb ^ ((row & 7) << 4)));
        }
#pragma unroll
        for (int mf = 0; mf < 4; ++mf)
#pragma unroll
            for (int nf = 0; nf < 4; ++nf)
                acc[mf][nf] = __builtin_amdgcn_mfma_f32_16x16x32_f16(
                    af[mf], bf[nf], acc[mf][nf], 0, 0, 0);
    }
    u16* Gb = G + (size_t)b * 2097152;
#pragma unroll
    for (int mf = 0; mf < 4; ++mf) {
        int o = os * 128 + wm * 64 + mf * 16 + (fq << 2);
#pragma unroll
        for (int nf = 0; nf < 4; ++nf) {
            int t = wn * 64 + nf * 16 + fr;
            f32x4 v = acc[mf][nf];
#pragma unroll
            for (int r = 0; r < 4; ++r)
                Gb[(size_t)(o + r) * 4096 + n * 128 + t] = f2h(v[r]);
        }
    }
}

// ---------------- GEMM1 v6: m3T = relu(G . SM^T + b3); SM built in LDS from taps --------
// Grid 520 = 130 (panel q = 65x2 batches) x 4 o-splits (quad-XCD co-location).
// BM=128, BN=128 cells, BK=64 (k = n*128+t; tile t64 -> n=t64>>1, thalf=(t64&1)*64).
// A dbuf 2x16KB staged from G; B dbuf 2x16KB built by tid<128 (zero + <=8 taps/cell).
// Counted vmcnt(4); buildB ordered BEFORE stageA so tap-wait doesn't drain the pipeline.
__global__ __launch_bounds__(256, 2) void mega_kernel(
        const u16* __restrict__ G, const int* __restrict__ tapT0,
        const u16* __restrict__ tapW, const float* __restrict__ b3,
        u16* __restrict__ m3T) {
    __shared__ alignas(16) char lds[65536];

    const int tid = threadIdx.x;
    const int lane = tid & 63, wv = tid >> 6;
    const int fr = lane & 15, fq = lane >> 4;
    const int swz = (fr & 7) << 4;
    const int wm = wv >> 1, wn = wv & 1;

    int i = blockIdx.x, q, s;
    if (i < 512) { int c = i >> 5, r = i & 31; s = r >> 3; q = c * 8 + (r & 7); }
    else         { int t2 = i - 512; q = 128 + (t2 >> 2); s = t2 & 3; }
    const int b = (q >= 65) ? 1 : 0;
    const int pi = q - 65 * b;
    const int cell0 = pi * 128;
    const int cn = (pi == 64) ? 64 : 128;
    const size_t brow0 = (size_t)b * 8256 + cell0;
    const int m0 = s * 128;
    const u16* Gb = G + (size_t)b * 2097152;

    f32x4 acc[4][4] = {};

    auto stageA = [&](int buf, int kt) {           // 4 global_load_lds
        char* A = lds + buf * 16384;
#pragma unroll
        for (int i2 = 0; i2 < 4; ++i2) {
            int off = i2 * 4096 + tid * 16;
            int row = off >> 7, colb = off & 127;
            int scol = colb ^ ((row & 7) << 4);
            const u16* ga = Gb + (size_t)(m0 + row) * 4096 + kt + (scol >> 1);
            __builtin_amdgcn_global_load_lds(
                (const __attribute__((address_space(1))) void*)ga,
                (__attribute__((address_space(3))) void*)(A + off), 16, 0, 0);
        }
    };
    auto buildB = [&](int buf, int t64) {          // tid<128: zero row + scatter taps
        if (tid < 128) {
            char* Brow = lds + 32768 + buf * 16384 + tid * 128;
            int swzB = (tid & 7) << 4;
            f32x4 z = {0.f, 0.f, 0.f, 0.f};
#pragma unroll
            for (int ch = 0; ch < 8; ++ch)
                *(f32x4*)(Brow + ((ch * 16) ^ swzB)) = z;
            int cell = cell0 + (tid < cn ? tid : 0);
            int n = t64 >> 1, thalf = (t64 & 1) << 6;
            int e2 = n * 8256 + cell;
            int t0 = tapT0[e2];
            const u64* wp = (const u64*)(tapW + (size_t)e2 * 8);
            u64 w01 = wp[0], w23 = wp[1];
#pragma unroll
            for (int k = 0; k < 8; ++k) {
                u16 wk = (u16)(((k < 4) ? w01 : w23) >> (16 * (k & 3)));
                int tt = t0 + k - thalf;
                if ((unsigned)tt < 64u)
                    *(u16*)(Brow + ((tt << 1) ^ swzB)) = wk;
            }
        }
    };

    buildB(0, 0);
    buildB(1, 1);
    stageA(0, 0);
    stageA(1, 64);
    asm volatile("s_waitcnt vmcnt(4) lgkmcnt(0)" ::: "memory");   // A0 + all B writes done
    __builtin_amdgcn_sched_barrier(0);
    __builtin_amdgcn_s_barrier();
    __builtin_amdgcn_sched_barrier(0);

    for (int t64 = 0; t64 < 64; ++t64) {
        const int cur = t64 & 1;
        const char* A = lds + cur * 16384;
        const char* Bp = lds + 32768 + cur * 16384;
#pragma unroll
        for (int kk = 0; kk < 2; ++kk) {
            const int kb = (kk * 64 + (fq << 4)) ^ swz;
            f16x8 af[4], bfr[4];
#pragma unroll
            for (int mf = 0; mf < 4; ++mf)
                af[mf] = *(const f16x8*)(A + (wm * 64 + mf * 16 + fr) * 128 + kb);
#pragma unroll
            for (int nf = 0; nf < 4; ++nf)
                bfr[nf] = *(const f16x8*)(Bp + (wn * 64 + nf * 16 + fr) * 128 + kb);
            __builtin_amdgcn_s_setprio(1);
#pragma unroll
            for (int mf = 0; mf < 4; ++mf)
#pragma unroll
                for (int nf = 0; nf < 4; ++nf)
                    acc[mf][nf] = __builtin_amdgcn_mfma_f32_16x16x32_f16(
                        af[mf], bfr[nf], acc[mf][nf], 0, 0, 0);
            __builtin_amdgcn_s_setprio(0);
        }
        __builtin_amdgcn_s_barrier();              // all waves done reading cur
        if (t64 < 62) {
            buildB(cur, t64 + 2);                  // taps first (their wait leaves A(t+1))
            stageA(cur, (t64 + 2) << 6);
            asm volatile("s_waitcnt vmcnt(4) lgkmcnt(0)" ::: "memory");  // A(t+1) + B writes
        } else {
            asm volatile("s_waitcnt vmcnt(0) lgkmcnt(0)" ::: "memory");
        }
        __builtin_amdgcn_sched_barrier(0);
        __builtin_amdgcn_s_barrier();
        __builtin_amdgcn_sched_barrier(0);
    }

    // epilogue: m3T[brow0+cl][o] = fp16(relu(acc + b3[o]))
#pragma unroll
    for (int mf = 0; mf < 4; ++mf) {
        int o = m0 + wm * 64 + mf * 16 + (fq << 2);
#pragma unroll
        for (int nf = 0; nf < 4; ++nf) {
            int cl = wn * 64 + nf * 16 + fr;
            if (cl < cn) {
                f32x4 v = acc[mf][nf];
                u64 pw = 0;
#pragma unroll
                for (int r = 0; r < 4; ++r) {
                    float z = fmaxf(v[r] + b3[o + r], 0.f);
                    pw |= (u64)f2h(z) << (16 * r);
                }
                *(u64*)(m3T + (brow0 + cl) * 512 + o) = pw;
            }
        }
    }
}

// ---------------- GEMM2: out = relu(W2 . m3 + b2), scatter via tab ----------------
__global__ __launch_bounds__(256) void gemm2_kernel(const u16* __restrict__ A,
                                                    const u16* __restrict__ B,
                                                    const float* __restrict__ bias,
                                                    const int* __restrict__ tab,
                                                    float* __restrict__ out) {
    __shared__ alignas(16) u16 As[64 * 64];
    __shared__ alignas(16) u16 Bs[128 * 64];
    const int tid = threadIdx.x;
    const int lane = tid & 63, wave = tid >> 6;
    const int m0 = blockIdx.x * 64;
    const int wr = wave & 1, wc = wave >> 1;
    const int fr = lane & 15, fk = (lane >> 4) * 16;
    f32x4 acc[2][4] = {};

    for (int kt = 0; kt < 512; kt += 64) {
#pragma unroll
        for (int i = 0; i < 2; ++i) {
            int off = i * 4096 + tid * 16;
            int row = off >> 7, colb = off & 127;
            const u16* ga = A + (size_t)(m0 + row) * 512 + kt + (colb >> 1);
            __builtin_amdgcn_global_load_lds(
                (const __attribute__((address_space(1))) void*)ga,
                (__attribute__((address_space(3))) void*)((char*)As + off), 16, 0, 0);
        }
#pragma unroll
        for (int i = 0; i < 4; ++i) {
            int off = i * 4096 + tid * 16;
            int row = off >> 7, colb = off & 127;
            const u16* gb = B + (size_t)row * 512 + kt + (colb >> 1);
            __builtin_amdgcn_global_load_lds(
                (const __attribute__((address_space(1))) void*)gb,
                (__attribute__((address_space(3))) void*)((char*)Bs + off), 16, 0, 0);
        }
        __syncthreads();
#pragma unroll
        for (int kk = 0; kk < 2; ++kk) {
            f16x8 af[2], bfr[4];
            const int kb = kk * 64 + fk;
#pragma unroll
            for (int mf = 0; mf < 2; ++mf)
                af[mf] = *(const f16x8*)((const char*)As + (wr * 32 + mf * 16 + fr) * 128 + kb);
#pragma unroll
            for (int nf = 0; nf < 4; ++nf)
                bfr[nf] = *(const f16x8*)((const char*)Bs + (wc * 64 + nf * 16 + fr) * 128 + kb);
#pragma unroll
            for (int mf = 0; mf < 2; ++mf)
#pragma unroll
                for (int nf = 0; nf < 4; ++nf)
                    acc[mf][nf] = __builtin_amdgcn_mfma_f32_16x16x32_f16(
                        af[mf], bfr[nf], acc[mf][nf], 0, 0, 0);
        }
        __syncthreads();
    }

#pragma unroll
    for (int mf = 0; mf < 2; ++mf) {
        int rbase = m0 + wr * 32 + mf * 16 + ((lane >> 4) << 2);
#pragma unroll
        for (int nf = 0; nf < 4; ++nf) {
            int o2 = wc * 64 + nf * 16 + fr;
            f32x4 v = acc[mf][nf];
#pragma unroll
            for (int r = 0; r < 4; ++r) {
                int colg = rbase + r;
                int b = (colg >= 8256) ? 1 : 0;
                int cell = colg - b * 8256;
                int dm = tab[cell];
                float z = fmaxf(v[r] + bias[o2], 0.f);
                out[((size_t)b << 21) + ((size_t)o2 << 14) + ((dm >> 8) << 7) + (dm & 255)] = z;
            }
        }
    }
}

// ws layout (bytes):
//   0         hT16   fp16 [2][128][128]           65536
//   65536     W3n    fp16 [32][512][128]          4194304
//   4259840   W2h    fp16 [128][512]              131072
//   4390912   c0     fp32 [128]                   512
//   4391424   tab    int  [8256] (alloc 16512)    66048
//   4457472   tapT0  i32  [264192]                1056768
//   5514240   tapW   fp16 [264192][8]             4227072
//   9741312   G      fp16 [2][512][4096]          8388608
//   18129920  m3T    fp16 [16512][512]            16908288  -> total ~35 MB
extern "C" void kernel_launch(void* const* d_in, const int* in_sizes, int n_in,
                              void* d_out, int out_size, void* d_ws, size_t ws_size,
                              hipStream_t stream) {
    const float* x     = (const float*)d_in[0];
    const float* w_red = (const float*)d_in[1];
    const float* b_red = (const float*)d_in[2];
    const float* w3d   = (const float*)d_in[3];
    const float* b3d   = (const float*)d_in[4];
    const float* w2d   = (const float*)d_in[5];
    const float* b2d   = (const float*)d_in[6];
    float* out = (float*)d_out;

    char* ws = (char*)d_ws;
    u16*   hT16  = (u16*)(ws + 0);
    u16*   W3n   = (u16*)(ws + 65536);
    u16*   W2h   = (u16*)(ws + 4259840);
    float* c0    = (float*)(ws + 4390912);
    int*   tab   = (int*)(ws + 4391424);
    int*   tapT0 = (int*)(ws + 4457472);
    u16*   tapW  = (u16*)(ws + 5514240);
    u16*   G     = (u16*)(ws + 9741312);
    u16*   m3T   = (u16*)(ws + 18129920);

    setup_kernel<<<1802, 256, 0, stream>>>(x, w_red, b_red, w3d, w2d, b3d, b2d,
                                           W3n, hT16, W2h, tab, c0, tapT0, tapW);
    gkern<<<256, 256, 0, stream>>>(W3n, hT16, G);
    mega_kernel<<<520, 256, 0, stream>>>(G, tapT0, tapW, b3d, m3T);
    gemm2_kernel<<<258, 256, 0, stream>>>(m3T, W2h, b2d, tab, out);
    fill_kernel<<<dim3(128, 2), 256, 0, stream>>>(c0, out);
}